// Round 1
// baseline (431.376 us; speedup 1.0000x reference)
//
#include <hip/hip_runtime.h>

#define C_ 96
#define H_ 512
#define W_ 96
#define HW_ 49152        // H_*W_
#define CHW_ 4718592     // C_*HW_
#define PIT 104          // LDS row pitch in f16 elements (208 B, 16B-aligned rows)
#define REG 9984         // 96*PIT elements per LDS region

typedef _Float16 f16x8 __attribute__((ext_vector_type(8)));
typedef _Float16 f16x4 __attribute__((ext_vector_type(4)));
typedef float    f32x4 __attribute__((ext_vector_type(4)));

#define MFMA16 __builtin_amdgcn_mfma_f32_16x16x32_f16

// LDS-only barrier: order our ds ops, do NOT drain vmcnt (prefetch loads /
// output stores stay in flight across the barrier — the whole point).
#define BAR() do { asm volatile("s_waitcnt lgkmcnt(0)" ::: "memory"); \
                   __builtin_amdgcn_s_barrier(); } while (0)

// Prepass: fold BN into the QKV weights.
//   W'[o][c] = W[o][c] * inv[c],  b'[o] = qkv_b[o] + sum_c W[o][c]*shift[c]
// where inv[c] = gamma/sqrt(var+eps), shift[c] = beta - mean*inv.
__global__ void prep_kernel(const float* __restrict__ wq,
                            const float* __restrict__ gamma,
                            const float* __restrict__ beta,
                            const float* __restrict__ mean,
                            const float* __restrict__ var,
                            const float* __restrict__ qkvb,
                            _Float16* __restrict__ whf,
                            float* __restrict__ bprime)
{
    int i = blockIdx.x * 256 + threadIdx.x;
    if (i < 3 * C_ * C_) {
        int c = i % C_;
        float iv = gamma[c] * rsqrtf(var[c] + 1e-5f);
        whf[i] = (_Float16)(wq[i] * iv);
    }
    if (i < 3 * C_) {
        float acc = qkvb[i];
        for (int c = 0; c < C_; ++c) {
            float iv = gamma[c] * rsqrtf(var[c] + 1e-5f);
            acc += wq[i * C_ + c] * (beta[c] - mean[c] * iv);
        }
        bprime[i] = acc;
    }
}

// Persistent kernel: 512 wgs (2/CU), each processes 8 consecutive (b,h) tiles.
// 6 waves; wave ws owns S/O row-strip [16ws,16ws+16).
__global__ __launch_bounds__(384, 3) void attn_kernel(
    const float* __restrict__ x,
    const _Float16* __restrict__ wqkv,
    const float* __restrict__ bprime,
    float* __restrict__ out)
{
    // 4 regions * 19968 B = 79872 B -> 2 blocks/CU
    __shared__ __align__(16) _Float16 smem[4 * REG];

    const int tid  = threadIdx.x;
    const int ws   = tid >> 6;    // wave 0..5
    const int lane = tid & 63;
    const int q4   = lane >> 4;   // quad 0..3
    const int n16  = lane & 15;
    const int w0   = 16 * ws + 4 * q4;

    _Float16* Rcur = smem;            // xn (phase 1), then V[c][w]   (ping)
    _Float16* Rnxt = smem + REG;      // staging target for next xn   (pong)
    _Float16* QP   = smem + 2 * REG;  // Q[w][c], then P[q][k] (strip-private)
    _Float16* Ks   = smem + 3 * REG;  // K[w][c]

    // 8 consecutive bh per wg; h0 = (blockIdx&63)*8, +7 <= 511 so b is constant.
    size_t base = (size_t)(blockIdx.x >> 6) * CHW_
                + (size_t)((blockIdx.x & 63) * 8) * W_;

    f32x4 xr[6], xrn[6];

    // ---- prologue: load + stage tile 0 (x kept in regs for residual) ----
    #pragma unroll
    for (int t6 = 0; t6 < 6; ++t6)
        xr[t6] = *(const f32x4*)(x + base + (size_t)(16 * t6 + n16) * HW_ + w0);
    #pragma unroll
    for (int t6 = 0; t6 < 6; ++t6) {
        const int c = 16 * t6 + n16;
        #pragma unroll
        for (int r = 0; r < 4; ++r)
            Rcur[(w0 + r) * PIT + c] = (_Float16)xr[t6][r];
    }
    BAR();

    const int obase = 48 * ws;            // waves 0-3: Q/K output rows
    const int ob    = 192 + 48 * (ws - 4); // waves 4-5: V output rows

    #pragma unroll 1
    for (int t = 0; t < 8; ++t) {
        // ---- prefetch next x tile (issue only; lands under phases 1-2) ----
        if (t < 7) {
            #pragma unroll
            for (int t6 = 0; t6 < 6; ++t6)
                xrn[t6] = *(const f32x4*)(x + base + W_
                              + (size_t)(16 * t6 + n16) * HW_ + w0);
        }

        // ---- phase 1: QKV = W' @ xn + b' ----
        f32x4 acc[18];
        if (ws < 4) {
            // normal orientation: D[o][w] (rows o = 4q4+r, cols w = n16)
            #pragma unroll
            for (int mt = 0; mt < 3; ++mt) {
                const f32x4 bb = *(const f32x4*)(bprime + obase + 16 * mt + 4 * q4);
                #pragma unroll
                for (int nt = 0; nt < 6; ++nt) acc[6 * mt + nt] = bb;
            }
            #pragma unroll
            for (int kk = 0; kk < 3; ++kk) {
                f16x8 bfr[6];
                #pragma unroll
                for (int nt = 0; nt < 6; ++nt)
                    bfr[nt] = *(const f16x8*)(Rcur + (16 * nt + n16) * PIT + 32 * kk + 8 * q4);
                #pragma unroll
                for (int mt = 0; mt < 3; ++mt) {
                    const f16x8 afr = *(const f16x8*)(wqkv + (obase + 16 * mt + n16) * 96 + 32 * kk + 8 * q4);
                    #pragma unroll
                    for (int nt = 0; nt < 6; ++nt)
                        acc[6 * mt + nt] = MFMA16(afr, bfr[nt], acc[6 * mt + nt], 0, 0, 0);
                }
            }
        } else {
            // swapped orientation for V: D[w][o] (rows w = 4q4+r, cols o = n16)
            // -> V store becomes vectorized b64 along w in [c][w] layout
            #pragma unroll
            for (int ot = 0; ot < 3; ++ot) {
                const float bv = bprime[ob + 16 * ot + n16];
                #pragma unroll
                for (int wt = 0; wt < 6; ++wt) acc[3 * wt + ot] = f32x4{bv, bv, bv, bv};
            }
            #pragma unroll
            for (int kk = 0; kk < 3; ++kk) {
                f16x8 xa[6];
                #pragma unroll
                for (int wt = 0; wt < 6; ++wt)
                    xa[wt] = *(const f16x8*)(Rcur + (16 * wt + n16) * PIT + 32 * kk + 8 * q4);
                #pragma unroll
                for (int ot = 0; ot < 3; ++ot) {
                    const f16x8 wb = *(const f16x8*)(wqkv + (ob + 16 * ot + n16) * 96 + 32 * kk + 8 * q4);
                    #pragma unroll
                    for (int wt = 0; wt < 6; ++wt)
                        acc[3 * wt + ot] = MFMA16(xa[wt], wb, acc[3 * wt + ot], 0, 0, 0);
                }
            }
        }
        BAR();   // all xn reads done -> V may overwrite Rcur

        if (ws < 4) {
            #pragma unroll
            for (int mt = 0; mt < 3; ++mt) {
                const int o = obase + 16 * mt + 4 * q4;
                #pragma unroll
                for (int nt = 0; nt < 6; ++nt) {
                    f16x4 pk;
                    #pragma unroll
                    for (int r = 0; r < 4; ++r) pk[r] = (_Float16)acc[6 * mt + nt][r];
                    const int w = 16 * nt + n16;
                    if (obase < 96) *(f16x4*)(QP + w * PIT + o) = pk;        // Q[w][c]
                    else            *(f16x4*)(Ks + w * PIT + (o - 96)) = pk; // K[w][c]
                }
            }
        } else {
            #pragma unroll
            for (int ot = 0; ot < 3; ++ot) {
                const int c = ob - 192 + 16 * ot + n16;
                #pragma unroll
                for (int wt = 0; wt < 6; ++wt) {
                    f16x4 pk;
                    #pragma unroll
                    for (int r = 0; r < 4; ++r) pk[r] = (_Float16)acc[3 * wt + ot][r];
                    *(f16x4*)(Rcur + c * PIT + 16 * wt + 4 * q4) = pk;       // V[c][w]
                }
            }
        }
        BAR();   // QKV visible to all waves

        // ---- phase 2: S^T = K Q^T (lane owns q-row = 16ws+n16), softmax ----
        f32x4 sacc[6];
        #pragma unroll
        for (int nt = 0; nt < 6; ++nt) sacc[nt] = f32x4{0.f, 0.f, 0.f, 0.f};
        #pragma unroll
        for (int kk = 0; kk < 3; ++kk) {
            const f16x8 qb = *(const f16x8*)(QP + (16 * ws + n16) * PIT + 32 * kk + 8 * q4);
            #pragma unroll
            for (int nt = 0; nt < 6; ++nt) {
                const f16x8 ka = *(const f16x8*)(Ks + (16 * nt + n16) * PIT + 32 * kk + 8 * q4);
                sacc[nt] = MFMA16(ka, qb, sacc[nt], 0, 0, 0);   // D[k][q]
            }
        }
        // lane holds S[q=16ws+n16][k=16nt+4q4+r]; reduce over own 24 + q4 pair
        float mr0 = sacc[0][0], mr1 = sacc[0][1], mr2 = sacc[0][2], mr3 = sacc[0][3];
        #pragma unroll
        for (int nt = 1; nt < 6; ++nt) {
            mr0 = fmaxf(mr0, sacc[nt][0]); mr1 = fmaxf(mr1, sacc[nt][1]);
            mr2 = fmaxf(mr2, sacc[nt][2]); mr3 = fmaxf(mr3, sacc[nt][3]);
        }
        float m = fmaxf(fmaxf(mr0, mr1), fmaxf(mr2, mr3));
        m = fmaxf(m, __shfl_xor(m, 16));
        m = fmaxf(m, __shfl_xor(m, 32));
        float sr0 = 0.f, sr1 = 0.f, sr2 = 0.f, sr3 = 0.f;
        #pragma unroll
        for (int nt = 0; nt < 6; ++nt) {
            sacc[nt][0] = __expf(sacc[nt][0] - m); sr0 += sacc[nt][0];
            sacc[nt][1] = __expf(sacc[nt][1] - m); sr1 += sacc[nt][1];
            sacc[nt][2] = __expf(sacc[nt][2] - m); sr2 += sacc[nt][2];
            sacc[nt][3] = __expf(sacc[nt][3] - m); sr3 += sacc[nt][3];
        }
        float s = (sr0 + sr1) + (sr2 + sr3);
        s += __shfl_xor(s, 16);
        s += __shfl_xor(s, 32);
        const float pinv = 1.0f / s;
        // store NORMALIZED P[q][k] (own row -> no barrier; b64 vectorized)
        #pragma unroll
        for (int nt = 0; nt < 6; ++nt) {
            f16x4 pk;
            #pragma unroll
            for (int r = 0; r < 4; ++r) pk[r] = (_Float16)(sacc[nt][r] * pinv);
            *(f16x4*)(QP + (16 * ws + n16) * PIT + 16 * nt + 4 * q4) = pk;
        }

        // ---- phase 3: O[q][c] = sum_k P[q][k] V[c][k] ----
        f32x4 oacc[6];
        #pragma unroll
        for (int nt = 0; nt < 6; ++nt) oacc[nt] = f32x4{0.f, 0.f, 0.f, 0.f};
        #pragma unroll
        for (int kk = 0; kk < 3; ++kk) {
            const f16x8 pa = *(const f16x8*)(QP + (16 * ws + n16) * PIT + 32 * kk + 8 * q4);
            #pragma unroll
            for (int nt = 0; nt < 6; ++nt) {
                const f16x8 vb = *(const f16x8*)(Rcur + (16 * nt + n16) * PIT + 32 * kk + 8 * q4);
                oacc[nt] = MFMA16(pa, vb, oacc[nt], 0, 0, 0);
            }
        }

        // ---- stage next xn into Rnxt (compiler waits vmcnt on first xrn use) ----
        if (t < 7) {
            #pragma unroll
            for (int t6 = 0; t6 < 6; ++t6) {
                const int c = 16 * t6 + n16;
                #pragma unroll
                for (int r = 0; r < 4; ++r)
                    Rnxt[(w0 + r) * PIT + c] = (_Float16)xrn[t6][r];
            }
        }

        // ---- epilogue: residual add + coalesced f32x4 store ----
        #pragma unroll
        for (int nt = 0; nt < 6; ++nt) {
            f32x4 o4;
            #pragma unroll
            for (int r = 0; r < 4; ++r) o4[r] = oacc[nt][r] + xr[nt][r];
            *(f32x4*)(out + base + (size_t)(16 * nt + n16) * HW_ + w0) = o4;
        }

        // rotate for next tile
        #pragma unroll
        for (int t6 = 0; t6 < 6; ++t6) xr[t6] = xrn[t6];
        base += W_;
        { _Float16* tmp = Rcur; Rcur = Rnxt; Rnxt = tmp; }
        BAR();   // Rnxt xn writes complete; QP/Ks free for next phase 1
    }
}

extern "C" void kernel_launch(void* const* d_in, const int* in_sizes, int n_in,
                              void* d_out, int out_size, void* d_ws, size_t ws_size,
                              hipStream_t stream)
{
    const float* x     = (const float*)d_in[0];
    const float* gamma = (const float*)d_in[1];
    const float* beta  = (const float*)d_in[2];
    const float* mean  = (const float*)d_in[3];
    const float* var   = (const float*)d_in[4];
    const float* qkvw  = (const float*)d_in[5];
    const float* qkvb  = (const float*)d_in[6];
    float* out = (float*)d_out;

    _Float16* whf    = (_Float16*)d_ws;                    // 288*96 f16 = 55296 B
    float*    bprime = (float*)((char*)d_ws + 55296);      // 288 f32  = 1152 B

    prep_kernel<<<108, 256, 0, stream>>>(qkvw, gamma, beta, mean, var, qkvb, whf, bprime);
    attn_kernel<<<512, 384, 0, stream>>>(x, whf, bprime, out);
}

// Round 2
// 343.235 us; speedup vs baseline: 1.2568x; 1.2568x over previous
//
#include <hip/hip_runtime.h>

#define C_ 96
#define H_ 512
#define W_ 96
#define HW_ 49152        // H_*W_
#define CHW_ 4718592     // C_*HW_
#define PIT 104          // LDS row pitch in f16 elements (208 B, 16B-aligned rows)
#define REG 9984         // 96*PIT elements per region

typedef _Float16 f16x8 __attribute__((ext_vector_type(8)));
typedef _Float16 f16x4 __attribute__((ext_vector_type(4)));
typedef _Float16 f16x2 __attribute__((ext_vector_type(2)));
typedef float    f32x4 __attribute__((ext_vector_type(4)));
typedef int      i32x4 __attribute__((ext_vector_type(4)));

#define MFMA16 __builtin_amdgcn_mfma_f32_16x16x32_f16

// LDS-only barrier: order ds ops without draining vmcnt (global loads/stores
// stay in flight). sched_barrier(0) fences compiler code motion (rule #18).
#define BAR() do { __builtin_amdgcn_sched_barrier(0); \
                   asm volatile("s_waitcnt lgkmcnt(0)" ::: "memory"); \
                   __builtin_amdgcn_s_barrier(); \
                   __builtin_amdgcn_sched_barrier(0); } while (0)

// Prepass: fold BN into the QKV weights.
//   W'[o][c] = W[o][c] * inv[c],  b'[o] = qkv_b[o] + sum_c W[o][c]*shift[c]
__global__ void prep_kernel(const float* __restrict__ wq,
                            const float* __restrict__ gamma,
                            const float* __restrict__ beta,
                            const float* __restrict__ mean,
                            const float* __restrict__ var,
                            const float* __restrict__ qkvb,
                            _Float16* __restrict__ whf,
                            float* __restrict__ bprime)
{
    int i = blockIdx.x * 256 + threadIdx.x;
    if (i < 3 * C_ * C_) {
        int c = i % C_;
        float iv = gamma[c] * rsqrtf(var[c] + 1e-5f);
        whf[i] = (_Float16)(wq[i] * iv);
    }
    if (i < 3 * C_) {
        float acc = qkvb[i];
        for (int c = 0; c < C_; ++c) {
            float iv = gamma[c] * rsqrtf(var[c] + 1e-5f);
            acc += wq[i * C_ + c] * (beta[c] - mean[c] * iv);
        }
        bprime[i] = acc;
    }
}

// One wg per (b,h). 6 waves. 2 LDS regions (39,936 B) -> 3 wg/CU at <=102 regs.
// Wave ws owns q-strip [16ws,16ws+16). Q lives in registers (shfl exchange);
// K region is reused for P after the phase-2 barrier.
__global__ __launch_bounds__(384, 5) void attn_kernel(
    const float* __restrict__ x,
    const _Float16* __restrict__ wqkv,
    const float* __restrict__ bprime,
    float* __restrict__ out)
{
    __shared__ __align__(16) _Float16 smem[2 * REG];
    _Float16* XV = smem;           // xn[w][c] (phase 1), then V[c][w]
    _Float16* KP = smem + REG;     // K[w][o] (phases 1-2), then P[q][k]

    const int tid  = threadIdx.x;
    const int ws   = tid >> 6;    // wave 0..5
    const int lane = tid & 63;
    const int q4   = lane >> 4;   // quad 0..3
    const int n16  = lane & 15;
    const int w0   = 16 * ws + 4 * q4;

    const int bh = blockIdx.x;
    const size_t base = (size_t)(bh >> 9) * CHW_ + (size_t)(bh & 511) * W_;

    // ---- phase 0: load x (kept in regs for residual), xn -> LDS [w][c] ----
    f32x4 xr[6];
    #pragma unroll
    for (int t = 0; t < 6; ++t)
        xr[t] = *(const f32x4*)(x + base + (size_t)(16 * t + n16) * HW_ + w0);
    #pragma unroll
    for (int t = 0; t < 6; ++t) {
        const int c = 16 * t + n16;
        #pragma unroll
        for (int r = 0; r < 4; ++r)
            XV[(w0 + r) * PIT + c] = (_Float16)xr[t][r];
    }
    BAR();

    // ---- phase 1a: Q pass — own w-strip, ALL 96 o-rows. D[o][w=16ws+n16]. ----
    f32x4 qac[6];
    #pragma unroll
    for (int ot = 0; ot < 6; ++ot)
        qac[ot] = *(const f32x4*)(bprime + 16 * ot + 4 * q4);
    #pragma unroll
    for (int kk = 0; kk < 3; ++kk) {
        const f16x8 bfr = *(const f16x8*)(XV + (16 * ws + n16) * PIT + 32 * kk + 8 * q4);
        #pragma unroll
        for (int ot = 0; ot < 6; ++ot) {
            const f16x8 afr = *(const f16x8*)(wqkv + (16 * ot + n16) * 96 + 32 * kk + 8 * q4);
            qac[ot] = MFMA16(afr, bfr, qac[ot], 0, 0, 0);
        }
    }
    // pack f16 pairs, then shfl-exchange D-layout -> B-frag layout.
    // lane holds Q[q=16ws+n16][o=16ot+4q4+r]; needs Q[q][o=32kk+8q4+e].
    // Needed values live at lanes (q4'=2(q4&1)+{0,1}, same n16).
    int pq[6][2];
    #pragma unroll
    for (int ot = 0; ot < 6; ++ot) {
        #pragma unroll
        for (int jj = 0; jj < 2; ++jj) {
            f16x2 h;
            h[0] = (_Float16)qac[ot][2 * jj];
            h[1] = (_Float16)qac[ot][2 * jj + 1];
            pq[ot][jj] = __builtin_bit_cast(int, h);
        }
    }
    const int srcA = ((q4 & 1) << 5) | n16;   // lane of q4'=2(q4&1)
    const int srcB = srcA + 16;               // lane of q4'+1
    f16x8 qf[3];
    #pragma unroll
    for (int kk = 0; kk < 3; ++kk) {
        const int a0 = __shfl(pq[2 * kk][0], srcA), a1 = __shfl(pq[2 * kk][1], srcA);
        const int a2 = __shfl(pq[2 * kk][0], srcB), a3 = __shfl(pq[2 * kk][1], srcB);
        const int b0 = __shfl(pq[2 * kk + 1][0], srcA), b1 = __shfl(pq[2 * kk + 1][1], srcA);
        const int b2 = __shfl(pq[2 * kk + 1][0], srcB), b3 = __shfl(pq[2 * kk + 1][1], srcB);
        i32x4 u;
        u[0] = (q4 < 2) ? a0 : b0;   // ot* = 2kk + (q4>>1)
        u[1] = (q4 < 2) ? a1 : b1;
        u[2] = (q4 < 2) ? a2 : b2;
        u[3] = (q4 < 2) ? a3 : b3;
        qf[kk] = __builtin_bit_cast(f16x8, u);
    }

    // ---- phase 1b: K pass — o-rows [96+16ws,+16) x all w. D[o][w]. ----
    f32x4 kac[6];
    {
        const f32x4 bb = *(const f32x4*)(bprime + 96 + 16 * ws + 4 * q4);
        #pragma unroll
        for (int nt = 0; nt < 6; ++nt) kac[nt] = bb;
    }
    #pragma unroll
    for (int kk = 0; kk < 3; ++kk) {
        const f16x8 afr = *(const f16x8*)(wqkv + (96 + 16 * ws + n16) * 96 + 32 * kk + 8 * q4);
        #pragma unroll
        for (int nt = 0; nt < 6; ++nt) {
            const f16x8 bfr = *(const f16x8*)(XV + (16 * nt + n16) * PIT + 32 * kk + 8 * q4);
            kac[nt] = MFMA16(afr, bfr, kac[nt], 0, 0, 0);
        }
    }
    // store K[w][o_local] (b64 along o; KP region free from start)
    #pragma unroll
    for (int nt = 0; nt < 6; ++nt) {
        f16x4 pk;
        #pragma unroll
        for (int r = 0; r < 4; ++r) pk[r] = (_Float16)kac[nt][r];
        *(f16x4*)(KP + (16 * nt + n16) * PIT + 16 * ws + 4 * q4) = pk;
    }

    // ---- phase 1c: V pass — swapped D[w][c_v], c_v strip [16ws,+16). ----
    f32x4 vac[6];
    {
        const float bv = bprime[192 + 16 * ws + n16];
        #pragma unroll
        for (int nt = 0; nt < 6; ++nt) vac[nt] = f32x4{bv, bv, bv, bv};
    }
    #pragma unroll
    for (int kk = 0; kk < 3; ++kk) {
        const f16x8 wb = *(const f16x8*)(wqkv + (192 + 16 * ws + n16) * 96 + 32 * kk + 8 * q4);
        #pragma unroll
        for (int nt = 0; nt < 6; ++nt) {
            const f16x8 xa = *(const f16x8*)(XV + (16 * nt + n16) * PIT + 32 * kk + 8 * q4);
            vac[nt] = MFMA16(xa, wb, vac[nt], 0, 0, 0);
        }
    }
    BAR();   // all xn reads done everywhere; K stores visible

    // V -> XV[c][w] (b64 along w), c = 16ws+n16 strip
    #pragma unroll
    for (int nt = 0; nt < 6; ++nt) {
        f16x4 pk;
        #pragma unroll
        for (int r = 0; r < 4; ++r) pk[r] = (_Float16)vac[nt][r];
        *(f16x4*)(XV + (16 * ws + n16) * PIT + 16 * nt + 4 * q4) = pk;
    }

    // ---- phase 2: S^T = K Q^T (lane owns q-row 16ws+n16); in-lane softmax ----
    f32x4 sacc[6];
    #pragma unroll
    for (int nt = 0; nt < 6; ++nt) sacc[nt] = f32x4{0.f, 0.f, 0.f, 0.f};
    #pragma unroll
    for (int kk = 0; kk < 3; ++kk) {
        #pragma unroll
        for (int nt = 0; nt < 6; ++nt) {
            const f16x8 ka = *(const f16x8*)(KP + (16 * nt + n16) * PIT + 32 * kk + 8 * q4);
            sacc[nt] = MFMA16(ka, qf[kk], sacc[nt], 0, 0, 0);   // D[k][q]
        }
    }
    float mr0 = sacc[0][0], mr1 = sacc[0][1], mr2 = sacc[0][2], mr3 = sacc[0][3];
    #pragma unroll
    for (int nt = 1; nt < 6; ++nt) {
        mr0 = fmaxf(mr0, sacc[nt][0]); mr1 = fmaxf(mr1, sacc[nt][1]);
        mr2 = fmaxf(mr2, sacc[nt][2]); mr3 = fmaxf(mr3, sacc[nt][3]);
    }
    float m = fmaxf(fmaxf(mr0, mr1), fmaxf(mr2, mr3));
    m = fmaxf(m, __shfl_xor(m, 16));
    m = fmaxf(m, __shfl_xor(m, 32));
    float sr0 = 0.f, sr1 = 0.f, sr2 = 0.f, sr3 = 0.f;
    #pragma unroll
    for (int nt = 0; nt < 6; ++nt) {
        sacc[nt][0] = __expf(sacc[nt][0] - m); sr0 += sacc[nt][0];
        sacc[nt][1] = __expf(sacc[nt][1] - m); sr1 += sacc[nt][1];
        sacc[nt][2] = __expf(sacc[nt][2] - m); sr2 += sacc[nt][2];
        sacc[nt][3] = __expf(sacc[nt][3] - m); sr3 += sacc[nt][3];
    }
    float s = (sr0 + sr1) + (sr2 + sr3);
    s += __shfl_xor(s, 16);
    s += __shfl_xor(s, 32);
    const float pinv = 1.0f / s;

    BAR();   // all K reads done -> P may overwrite KP; V stores visible

    // store NORMALIZED P[q][k] into KP (own row; b64)
    #pragma unroll
    for (int nt = 0; nt < 6; ++nt) {
        f16x4 pk;
        #pragma unroll
        for (int r = 0; r < 4; ++r) pk[r] = (_Float16)(sacc[nt][r] * pinv);
        *(f16x4*)(KP + (16 * ws + n16) * PIT + 16 * nt + 4 * q4) = pk;
    }

    // ---- phase 3: O[q][c] = sum_k P[q][k] V[c][k] ----
    f32x4 oacc[6];
    #pragma unroll
    for (int nt = 0; nt < 6; ++nt) oacc[nt] = f32x4{0.f, 0.f, 0.f, 0.f};
    #pragma unroll
    for (int kk = 0; kk < 3; ++kk) {
        const f16x8 pa = *(const f16x8*)(KP + (16 * ws + n16) * PIT + 32 * kk + 8 * q4);
        #pragma unroll
        for (int nt = 0; nt < 6; ++nt) {
            const f16x8 vb = *(const f16x8*)(XV + (16 * nt + n16) * PIT + 32 * kk + 8 * q4);
            oacc[nt] = MFMA16(pa, vb, oacc[nt], 0, 0, 0);
        }
    }

    // ---- epilogue: residual add + coalesced f32x4 store ----
    #pragma unroll
    for (int nt = 0; nt < 6; ++nt) {
        f32x4 o4;
        #pragma unroll
        for (int r = 0; r < 4; ++r) o4[r] = oacc[nt][r] + xr[nt][r];
        *(f32x4*)(out + base + (size_t)(16 * nt + n16) * HW_ + w0) = o4;
    }
}

extern "C" void kernel_launch(void* const* d_in, const int* in_sizes, int n_in,
                              void* d_out, int out_size, void* d_ws, size_t ws_size,
                              hipStream_t stream)
{
    const float* x     = (const float*)d_in[0];
    const float* gamma = (const float*)d_in[1];
    const float* beta  = (const float*)d_in[2];
    const float* mean  = (const float*)d_in[3];
    const float* var   = (const float*)d_in[4];
    const float* qkvw  = (const float*)d_in[5];
    const float* qkvb  = (const float*)d_in[6];
    float* out = (float*)d_out;

    _Float16* whf    = (_Float16*)d_ws;                    // 288*96 f16 = 55296 B
    float*    bprime = (float*)((char*)d_ws + 55296);      // 288 f32  = 1152 B

    prep_kernel<<<108, 256, 0, stream>>>(qkvw, gamma, beta, mean, var, qkvb, whf, bprime);
    attn_kernel<<<4096, 384, 0, stream>>>(x, whf, bprime, out);
}